// Round 7
// baseline (266.641 us; speedup 1.0000x reference)
//
#include <hip/hip_runtime.h>
#include <math.h>

// Problem: B=64, N=4096, K=128. Labels C in [0,128).
// out[b,i,k] = (rank(C[b,i]) == k) ? u : ndtri(clip(U,1e-7,1-1e-7) * Phi(u))
// where u = mu + sigma*eps[b,i], rank = index of C[b,i] in sorted unique(C).
//
// Structure (v7 = verified v3 map + memset-free bitmap):
//   ws[0..255] : 16 slots x uint4 — per-block presence bitmaps (plain stores,
//                no zero-init needed; each block overwrites its own slot).
// Pass 1 (bitmap_kernel): 16 blocks, grid-stride over C (1 MiB); each block
//   reduces its labels to a 128-bit bitmap and stores it to slot[blockIdx].
//   NO hipMemsetAsync dispatch anymore (was ~3-5 us of launch overhead).
// Pass 2 (map_kernel): ONE float4 per thread (fully coalesced; R4: coarsening
//   with partial-line NT stores = 1.6x write amp, 29% HBM. R5: NT U loads
//   cost ~9 us. R6: pk-fma polys neutral -> VALU is fully hidden).
//   Rank = popcount over the OR of the 16 slots (wave-uniform reads ->
//   scalar loads + s_or, free on the SALU pipe). NT store for write-once out.

typedef float vfloat4 __attribute__((ext_vector_type(4)));

// ---------------------------------------------------------------------------
// Acklam's inverse normal CDF, fp32, branchless. Both rational paths are
// evaluated (tail probability ~11%/element -> every wave diverges anyway),
// then num/den/scale are selected and ONE rcp is paid instead of two.
// Per-lane arithmetic is bit-identical to the branched version.
__device__ __forceinline__ float ndtri_fast(float p) {
    const float omp  = 1.0f - p;
    const bool upper = p > 0.5f;
    const float pm   = upper ? omp : p;   // min(p, 1-p)
    const bool tail  = pm < 0.02425f;

    // ---- tail branch values (valid/finite for all lanes: pm in (0, 0.5])
    float qt = sqrtf(-2.0f * __logf(pm));
    float numT = -0.007784894002430293f;
    numT = fmaf(numT, qt, -0.3223964580411365f);
    numT = fmaf(numT, qt, -2.400758277161838f);
    numT = fmaf(numT, qt, -2.549732539343734f);
    numT = fmaf(numT, qt,  4.374664141464968f);
    numT = fmaf(numT, qt,  2.938163982698783f);
    float denT = 0.007784695709041462f;
    denT = fmaf(denT, qt, 0.3224671290700398f);
    denT = fmaf(denT, qt, 2.445134137142996f);
    denT = fmaf(denT, qt, 3.754408661907416f);
    denT = fmaf(denT, qt, 1.0f);

    // ---- central branch values
    float qc = p - 0.5f;
    float r  = qc * qc;
    float numC = -39.69683028665376f;
    numC = fmaf(numC, r,  220.9460984245205f);
    numC = fmaf(numC, r, -275.9285104469687f);
    numC = fmaf(numC, r,  138.3577518672690f);
    numC = fmaf(numC, r,  -30.66479806614716f);
    numC = fmaf(numC, r,    2.506628277459239f);
    float denC = -54.47609879822406f;
    denC = fmaf(denC, r,  161.5858368580409f);
    denC = fmaf(denC, r, -155.6989798598866f);
    denC = fmaf(denC, r,   66.80131188771972f);
    denC = fmaf(denC, r,  -13.28068155288572f);
    denC = fmaf(denC, r,    1.0f);

    // ---- select + single rcp
    float num = tail ? numT : numC;
    float den = tail ? denT : denC;
    float s   = tail ? (upper ? -1.0f : 1.0f) : qc;
    return s * num * __builtin_amdgcn_rcpf(den);
}

__device__ __forceinline__ void set_label_bit(int c, unsigned& m0, unsigned& m1,
                                              unsigned& m2, unsigned& m3) {
    unsigned bit = 1u << (c & 31);
    int w = (c >> 5) & 3;
    if      (w == 0) m0 |= bit;
    else if (w == 1) m1 |= bit;
    else if (w == 2) m2 |= bit;
    else             m3 |= bit;
}

#define BITMAP_BLOCKS 16

// ---------------------------------------------------------------------------
// Pass 1: per-block presence bitmap into a private slot (no init required).
__global__ void __launch_bounds__(256) bitmap_kernel(
    const int* __restrict__ C,
    uint4* __restrict__ slots,
    int n)
{
    __shared__ unsigned sm[4];
    if (threadIdx.x < 4) sm[threadIdx.x] = 0u;
    __syncthreads();

    unsigned m0 = 0, m1 = 0, m2 = 0, m3 = 0;

    int n4 = n >> 2;                         // int4 chunks (n % 4 == 0 here)
    int stride = BITMAP_BLOCKS * 256;
    for (int i = blockIdx.x * 256 + threadIdx.x; i < n4; i += stride) {
        int4 c = *reinterpret_cast<const int4*>(C + (i << 2));
        set_label_bit(c.x, m0, m1, m2, m3);
        set_label_bit(c.y, m0, m1, m2, m3);
        set_label_bit(c.z, m0, m1, m2, m3);
        set_label_bit(c.w, m0, m1, m2, m3);
    }
    // generic tail (not hit for this shape)
    for (int j = (n4 << 2) + blockIdx.x * 256 + threadIdx.x; j < n;
         j += stride)
        set_label_bit(C[j], m0, m1, m2, m3);

    #pragma unroll
    for (int off = 32; off > 0; off >>= 1) {
        m0 |= __shfl_down(m0, off, 64);
        m1 |= __shfl_down(m1, off, 64);
        m2 |= __shfl_down(m2, off, 64);
        m3 |= __shfl_down(m3, off, 64);
    }
    if ((threadIdx.x & 63) == 0) {
        if (m0) atomicOr(&sm[0], m0);
        if (m1) atomicOr(&sm[1], m1);
        if (m2) atomicOr(&sm[2], m2);
        if (m3) atomicOr(&sm[3], m3);
    }
    __syncthreads();
    if (threadIdx.x == 0) {
        uint4 v;
        v.x = sm[0]; v.y = sm[1]; v.z = sm[2]; v.w = sm[3];
        slots[blockIdx.x] = v;               // plain store, own slot
    }
}

// ---------------------------------------------------------------------------
// Pass 2: one thread per float4 (4 consecutive k of one row).
// u and Phi(u) recomputed per thread (bit-identical; verified neutral R3).
__global__ void __launch_bounds__(256) map_kernel(
    const int* __restrict__ C,
    const float* __restrict__ eps,
    const float* __restrict__ mu_p,
    const float* __restrict__ sigma_p,
    const float4* __restrict__ U4,
    const uint4* __restrict__ slots,
    float4* __restrict__ out4,
    int total4)
{
    int idx = blockIdx.x * blockDim.x + threadIdx.x;
    if (idx >= total4) return;
    int row = idx >> 5;        // K/4 = 32 float4 per row
    int k0  = (idx & 31) << 2;

    float4 Uv = U4[idx];       // plain coalesced load (NT load cost ~9us, R5)
    float  e  = eps[row];      // 32 threads share each value -> L1 broadcast
    int    c  = C[row];

    // OR of the 16 per-block bitmaps. Wave-uniform addresses on a readonly
    // pointer -> scalar loads + s_or (SALU pipe, hidden under VMEM/VALU).
    uint4 w = slots[0];
    #pragma unroll
    for (int s = 1; s < BITMAP_BLOCKS; ++s) {
        uint4 t = slots[s];
        w.x |= t.x; w.y |= t.y; w.z |= t.z; w.w |= t.w;
    }

    const float sg = sigma_p[0];   // uniform address -> scalar load
    const float mu = mu_p[0];
    float u   = fmaf(sg, e, mu);
    float phi = 0.5f * erfcf(-u * 0.7071067811865476f);

    // rank = popcount of presence bits strictly below c
    int cw = c >> 5;
    unsigned below = (1u << (c & 31)) - 1u;
    int rank = __popc(w.x & ((0 < cw) ? 0xFFFFFFFFu : ((0 == cw) ? below : 0u)))
             + __popc(w.y & ((1 < cw) ? 0xFFFFFFFFu : ((1 == cw) ? below : 0u)))
             + __popc(w.z & ((2 < cw) ? 0xFFFFFFFFu : ((2 == cw) ? below : 0u)))
             + __popc(w.w & ((3 < cw) ? 0xFFFFFFFFu : ((3 == cw) ? below : 0u)));

    const float lo = 1e-7f;
    const float hi = 0.99999988079071045f;  // fp32(1 - 1e-7), matches jnp.clip

    // clamp via v_med3_f32 (single instruction)
    float p0 = __builtin_amdgcn_fmed3f(Uv.x, lo, hi) * phi;
    float p1 = __builtin_amdgcn_fmed3f(Uv.y, lo, hi) * phi;
    float p2 = __builtin_amdgcn_fmed3f(Uv.z, lo, hi) * phi;
    float p3 = __builtin_amdgcn_fmed3f(Uv.w, lo, hi) * phi;

    float z0 = ndtri_fast(p0);
    float z1 = ndtri_fast(p1);
    float z2 = ndtri_fast(p2);
    float z3 = ndtri_fast(p3);

    vfloat4 o;
    o.x = (k0 + 0 == rank) ? u : z0;
    o.y = (k0 + 1 == rank) ? u : z1;
    o.z = (k0 + 2 == rank) ? u : z2;
    o.w = (k0 + 3 == rank) ? u : z3;

    // out is never re-read: stream it past the caches (full-line coalesced)
    __builtin_nontemporal_store(o, reinterpret_cast<vfloat4*>(&out4[idx]));
}

extern "C" void kernel_launch(void* const* d_in, const int* in_sizes, int n_in,
                              void* d_out, int out_size, void* d_ws, size_t ws_size,
                              hipStream_t stream) {
    const int*   C     = (const int*)d_in[0];
    const float* eps   = (const float*)d_in[1];
    const float4* U4   = (const float4*)d_in[2];
    const float* mu    = (const float*)d_in[3];
    const float* sigma = (const float*)d_in[4];
    float4* out4 = (float4*)d_out;

    uint4* slots = (uint4*)d_ws;   // 16 x 16 B; overwritten every launch

    int n = in_sizes[0];           // B*N = 262144 rows
    int total4 = out_size / 4;     // float4 count (unchanged from verified baseline)

    // No memset needed: every slot is unconditionally overwritten by its block.
    bitmap_kernel<<<BITMAP_BLOCKS, 256, 0, stream>>>(C, slots, n);

    int mb = (total4 + 255) / 256;
    map_kernel<<<mb, 256, 0, stream>>>(C, eps, mu, sigma, U4,
                                       slots, out4, total4);
}

// Round 8
// 251.293 us; speedup vs baseline: 1.0611x; 1.0611x over previous
//
#include <hip/hip_runtime.h>
#include <math.h>

// Problem: B=64, N=4096, K=128. Labels C in [0,128).
// out[b,i,k] = (rank(C[b,i]) == k) ? u : ndtri(clip(U,1e-7,1-1e-7) * Phi(u))
// where u = mu + sigma*eps[b,i], rank = index of C[b,i] in sorted unique(C).
//
// Structure (v8 = verified R3 structure + same-row 2x coarsening):
//   ws[0..3] : 128-bit presence bitmap (zeroed via tiny memset — R7 showed the
//              "memset-free" 16-slot scheme costs +22 us: the per-thread
//              16-slot OR compiled to vector loads, ~134M extra load insts).
// Pass 1 (bitmap_kernel): presence bitmap only, 256 blocks, atomicOr.
// Pass 2 (map_kernel): each thread owns TWO float4s of ONE row: k-quad j and
//   j+16 (addresses lane-consecutive within each load instruction -> full
//   64-B line coverage, unlike R4's 64-B lane stride which caused 1.6x write
//   amp). erfcf/rank/mask/addressing amortized over 2 quads (~16% fewer VALU
//   insts per byte). Plain U loads (R5: NT loads cost ~9 us); NT stores for
//   the write-once output. Scalar Acklam ndtri (R6: pk-fma neutral),
//   branchless, single rcp — per-element math bit-identical since R0.

typedef float vfloat4 __attribute__((ext_vector_type(4)));

// ---------------------------------------------------------------------------
// Acklam's inverse normal CDF, fp32, branchless. Both rational paths are
// evaluated (tail probability ~11%/element -> every wave diverges anyway),
// then num/den/scale are selected and ONE rcp is paid instead of two.
// Per-lane arithmetic is bit-identical to the branched version.
__device__ __forceinline__ float ndtri_fast(float p) {
    const float omp  = 1.0f - p;
    const bool upper = p > 0.5f;
    const float pm   = upper ? omp : p;   // min(p, 1-p)
    const bool tail  = pm < 0.02425f;

    // ---- tail branch values (valid/finite for all lanes: pm in (0, 0.5])
    float qt = sqrtf(-2.0f * __logf(pm));
    float numT = -0.007784894002430293f;
    numT = fmaf(numT, qt, -0.3223964580411365f);
    numT = fmaf(numT, qt, -2.400758277161838f);
    numT = fmaf(numT, qt, -2.549732539343734f);
    numT = fmaf(numT, qt,  4.374664141464968f);
    numT = fmaf(numT, qt,  2.938163982698783f);
    float denT = 0.007784695709041462f;
    denT = fmaf(denT, qt, 0.3224671290700398f);
    denT = fmaf(denT, qt, 2.445134137142996f);
    denT = fmaf(denT, qt, 3.754408661907416f);
    denT = fmaf(denT, qt, 1.0f);

    // ---- central branch values
    float qc = p - 0.5f;
    float r  = qc * qc;
    float numC = -39.69683028665376f;
    numC = fmaf(numC, r,  220.9460984245205f);
    numC = fmaf(numC, r, -275.9285104469687f);
    numC = fmaf(numC, r,  138.3577518672690f);
    numC = fmaf(numC, r,  -30.66479806614716f);
    numC = fmaf(numC, r,    2.506628277459239f);
    float denC = -54.47609879822406f;
    denC = fmaf(denC, r,  161.5858368580409f);
    denC = fmaf(denC, r, -155.6989798598866f);
    denC = fmaf(denC, r,   66.80131188771972f);
    denC = fmaf(denC, r,  -13.28068155288572f);
    denC = fmaf(denC, r,    1.0f);

    // ---- select + single rcp
    float num = tail ? numT : numC;
    float den = tail ? denT : denC;
    float s   = tail ? (upper ? -1.0f : 1.0f) : qc;
    return s * num * __builtin_amdgcn_rcpf(den);
}

__device__ __forceinline__ void set_label_bit(int c, unsigned& m0, unsigned& m1,
                                              unsigned& m2, unsigned& m3) {
    unsigned bit = 1u << (c & 31);
    int w = (c >> 5) & 3;
    if      (w == 0) m0 |= bit;
    else if (w == 1) m1 |= bit;
    else if (w == 2) m2 |= bit;
    else             m3 |= bit;
}

// ---------------------------------------------------------------------------
// Pass 1: presence bitmap only. 4 labels per thread (int4 loads), 256 blocks.
__global__ void __launch_bounds__(256) bitmap_kernel(
    const int* __restrict__ C,
    unsigned* __restrict__ mask,
    int n)
{
    __shared__ unsigned sm[4];
    if (threadIdx.x < 4) sm[threadIdx.x] = 0u;
    __syncthreads();

    int i = blockIdx.x * blockDim.x + threadIdx.x;
    int base = i << 2;
    unsigned m0 = 0, m1 = 0, m2 = 0, m3 = 0;

    if (base + 3 < n) {
        int4 c = *reinterpret_cast<const int4*>(C + base);
        set_label_bit(c.x, m0, m1, m2, m3);
        set_label_bit(c.y, m0, m1, m2, m3);
        set_label_bit(c.z, m0, m1, m2, m3);
        set_label_bit(c.w, m0, m1, m2, m3);
    } else {
        for (int j = base; j < n && j < base + 4; ++j)
            set_label_bit(C[j], m0, m1, m2, m3);
    }

    #pragma unroll
    for (int off = 32; off > 0; off >>= 1) {
        m0 |= __shfl_down(m0, off, 64);
        m1 |= __shfl_down(m1, off, 64);
        m2 |= __shfl_down(m2, off, 64);
        m3 |= __shfl_down(m3, off, 64);
    }
    if ((threadIdx.x & 63) == 0) {
        if (m0) atomicOr(&sm[0], m0);
        if (m1) atomicOr(&sm[1], m1);
        if (m2) atomicOr(&sm[2], m2);
        if (m3) atomicOr(&sm[3], m3);
    }
    __syncthreads();
    if (threadIdx.x < 4) {
        unsigned v = sm[threadIdx.x];
        if (v) atomicOr(&mask[threadIdx.x], v);
    }
}

// ---------------------------------------------------------------------------
// Process one float4 of U into one output float4 (bit-identical math).
__device__ __forceinline__ vfloat4 do_quad(float4 Uv, float phi, float u,
                                           int rank, int kbase) {
    const float lo = 1e-7f;
    const float hi = 0.99999988079071045f;  // fp32(1 - 1e-7), matches jnp.clip
    float p0 = __builtin_amdgcn_fmed3f(Uv.x, lo, hi) * phi;
    float p1 = __builtin_amdgcn_fmed3f(Uv.y, lo, hi) * phi;
    float p2 = __builtin_amdgcn_fmed3f(Uv.z, lo, hi) * phi;
    float p3 = __builtin_amdgcn_fmed3f(Uv.w, lo, hi) * phi;
    float z0 = ndtri_fast(p0);
    float z1 = ndtri_fast(p1);
    float z2 = ndtri_fast(p2);
    float z3 = ndtri_fast(p3);
    vfloat4 o;
    o.x = (kbase + 0 == rank) ? u : z0;
    o.y = (kbase + 1 == rank) ? u : z1;
    o.z = (kbase + 2 == rank) ? u : z2;
    o.w = (kbase + 3 == rank) ? u : z3;
    return o;
}

// ---------------------------------------------------------------------------
// Pass 2: each thread handles float4 j and j+16 of one row (j = tid & 15).
// Both load/store instructions have lane-consecutive addresses (4 rows x
// 256 B fully-covered segments per wave instruction) -> full coalescing.
__global__ void __launch_bounds__(256) map_kernel(
    const int* __restrict__ C,
    const float* __restrict__ eps,
    const float* __restrict__ mu_p,
    const float* __restrict__ sigma_p,
    const float4* __restrict__ U4,
    const uint4* __restrict__ mask4,
    float4* __restrict__ out4,
    int total4)
{
    int tid = blockIdx.x * blockDim.x + threadIdx.x;
    int npairs = total4 >> 1;
    if (tid >= npairs) return;

    int row = tid >> 4;              // 16 threads per row
    int j   = tid & 15;              // quad 0..15; also handles quad j+16
    int idxA = (row << 5) + j;       // float4 index, k-quad j
    int idxB = idxA + 16;            // float4 index, k-quad j+16

    float4 UvA = U4[idxA];           // both loads fully coalesced
    float4 UvB = U4[idxB];
    float  e   = eps[row];           // 16 threads share -> L1 broadcast
    int    c   = C[row];
    uint4  w   = *mask4;             // same 16 B for all threads -> broadcast

    const float sg = sigma_p[0];     // uniform address -> scalar load
    const float mu = mu_p[0];
    float u   = fmaf(sg, e, mu);
    float phi = 0.5f * erfcf(-u * 0.7071067811865476f);

    // rank = popcount of presence bits strictly below c  (once per 2 quads)
    int cw = c >> 5;
    unsigned below = (1u << (c & 31)) - 1u;
    int rank = __popc(w.x & ((0 < cw) ? 0xFFFFFFFFu : ((0 == cw) ? below : 0u)))
             + __popc(w.y & ((1 < cw) ? 0xFFFFFFFFu : ((1 == cw) ? below : 0u)))
             + __popc(w.z & ((2 < cw) ? 0xFFFFFFFFu : ((2 == cw) ? below : 0u)))
             + __popc(w.w & ((3 < cw) ? 0xFFFFFFFFu : ((3 == cw) ? below : 0u)));

    int k0 = j << 2;
    vfloat4 oA = do_quad(UvA, phi, u, rank, k0);
    vfloat4 oB = do_quad(UvB, phi, u, rank, k0 + 64);

    // out is never re-read: stream it past the caches (full-line coalesced)
    __builtin_nontemporal_store(oA, reinterpret_cast<vfloat4*>(&out4[idxA]));
    __builtin_nontemporal_store(oB, reinterpret_cast<vfloat4*>(&out4[idxB]));
}

extern "C" void kernel_launch(void* const* d_in, const int* in_sizes, int n_in,
                              void* d_out, int out_size, void* d_ws, size_t ws_size,
                              hipStream_t stream) {
    const int*   C     = (const int*)d_in[0];
    const float* eps   = (const float*)d_in[1];
    const float4* U4   = (const float4*)d_in[2];
    const float* mu    = (const float*)d_in[3];
    const float* sigma = (const float*)d_in[4];
    float4* out4 = (float4*)d_out;

    unsigned* mask = (unsigned*)d_ws;

    int n = in_sizes[0];           // B*N = 262144 rows
    int total4 = out_size / 4;     // float4 count (unchanged from verified baseline)

    // ws is re-poisoned to 0xAA before every timed launch — zero the bitmap.
    (void)hipMemsetAsync(d_ws, 0, 4 * sizeof(unsigned), stream);

    int n4 = (n + 3) >> 2;
    int bb = (n4 + 255) / 256;
    bitmap_kernel<<<bb, 256, 0, stream>>>(C, mask, n);

    int npairs = total4 >> 1;      // 2 float4 per thread (total4 % 32 == 0)
    int mb = (npairs + 255) / 256;
    map_kernel<<<mb, 256, 0, stream>>>(C, eps, mu, sigma, U4,
                                       (const uint4*)mask, out4, total4);
}

// Round 9
// 244.196 us; speedup vs baseline: 1.0919x; 1.0291x over previous
//
#include <hip/hip_runtime.h>
#include <math.h>

// Problem: B=64, N=4096, K=128. Labels C in [0,128).
// out[b,i,k] = (rank(C[b,i]) == k) ? u : ndtri(clip(U,1e-7,1-1e-7) * Phi(u))
// where u = mu + sigma*eps[b,i], rank = index of C[b,i] in sorted unique(C).
//
// Structure (v9 = exact revert to verified-best R3, 241.9 us):
//   ws[0..3] : 128-bit presence bitmap over label values (zeroed via tiny memset)
// Pass 1 (bitmap_kernel): presence bitmap only — reads just C (1 MiB, ~2 us)
// Pass 2 (map_kernel): ONE float4 per thread (fully coalesced).
// Session evidence for this exact shape:
//   R4: 4x coarsening (64-B lane stride) -> 29% HBM, 1.6x write amp, +52 us
//   R5: nontemporal U loads -> +9 us
//   R6: pk-fma packed polys -> neutral
//   R7: memset-free 16-slot bitmap -> per-thread slot ORs became vector
//       loads (~134M extra), +22 us
//   R8: 2x same-row coarsening (perfect coalescing, fewer insts/byte) ->
//       still +9 us; counters showed VALUBusy 73%/HBM 30% -> map is at its
//       irreducible-VALU floor (both Acklam branches must run: tail prob
//       ~11.5%/elem -> every wave mixed; numerics must stay bit-identical
//       since absmax sits at exactly 2^-6, plausibly at the threshold).

// Native clang vector type — __builtin_nontemporal_* rejects
// HIP_vector_type<float,4> but accepts ext_vector_type.
typedef float vfloat4 __attribute__((ext_vector_type(4)));

// ---------------------------------------------------------------------------
// Acklam's inverse normal CDF, fp32, branchless. Both rational paths are
// evaluated (tail probability ~11%/element -> every wave diverges anyway),
// then num/den/scale are selected and ONE rcp is paid instead of two.
// Per-lane arithmetic is bit-identical to the branched version.
__device__ __forceinline__ float ndtri_fast(float p) {
    const float omp  = 1.0f - p;
    const bool upper = p > 0.5f;
    const float pm   = upper ? omp : p;   // min(p, 1-p)
    const bool tail  = pm < 0.02425f;

    // ---- tail branch values (valid/finite for all lanes: pm in (0, 0.5])
    float qt = sqrtf(-2.0f * __logf(pm));
    float numT = -0.007784894002430293f;
    numT = fmaf(numT, qt, -0.3223964580411365f);
    numT = fmaf(numT, qt, -2.400758277161838f);
    numT = fmaf(numT, qt, -2.549732539343734f);
    numT = fmaf(numT, qt,  4.374664141464968f);
    numT = fmaf(numT, qt,  2.938163982698783f);
    float denT = 0.007784695709041462f;
    denT = fmaf(denT, qt, 0.3224671290700398f);
    denT = fmaf(denT, qt, 2.445134137142996f);
    denT = fmaf(denT, qt, 3.754408661907416f);
    denT = fmaf(denT, qt, 1.0f);

    // ---- central branch values
    float qc = p - 0.5f;
    float r  = qc * qc;
    float numC = -39.69683028665376f;
    numC = fmaf(numC, r,  220.9460984245205f);
    numC = fmaf(numC, r, -275.9285104469687f);
    numC = fmaf(numC, r,  138.3577518672690f);
    numC = fmaf(numC, r,  -30.66479806614716f);
    numC = fmaf(numC, r,    2.506628277459239f);
    float denC = -54.47609879822406f;
    denC = fmaf(denC, r,  161.5858368580409f);
    denC = fmaf(denC, r, -155.6989798598866f);
    denC = fmaf(denC, r,   66.80131188771972f);
    denC = fmaf(denC, r,  -13.28068155288572f);
    denC = fmaf(denC, r,    1.0f);

    // ---- select + single rcp
    float num = tail ? numT : numC;
    float den = tail ? denT : denC;
    float s   = tail ? (upper ? -1.0f : 1.0f) : qc;
    return s * num * __builtin_amdgcn_rcpf(den);
}

__device__ __forceinline__ void set_label_bit(int c, unsigned& m0, unsigned& m1,
                                              unsigned& m2, unsigned& m3) {
    unsigned bit = 1u << (c & 31);
    int w = (c >> 5) & 3;
    if      (w == 0) m0 |= bit;
    else if (w == 1) m1 |= bit;
    else if (w == 2) m2 |= bit;
    else             m3 |= bit;
}

// ---------------------------------------------------------------------------
// Pass 1: presence bitmap only. 4 labels per thread (int4 loads).
__global__ void __launch_bounds__(256) bitmap_kernel(
    const int* __restrict__ C,
    unsigned* __restrict__ mask,
    int n)
{
    __shared__ unsigned sm[4];
    if (threadIdx.x < 4) sm[threadIdx.x] = 0u;
    __syncthreads();

    int i = blockIdx.x * blockDim.x + threadIdx.x;
    int base = i << 2;
    unsigned m0 = 0, m1 = 0, m2 = 0, m3 = 0;

    if (base + 3 < n) {
        int4 c = *reinterpret_cast<const int4*>(C + base);
        set_label_bit(c.x, m0, m1, m2, m3);
        set_label_bit(c.y, m0, m1, m2, m3);
        set_label_bit(c.z, m0, m1, m2, m3);
        set_label_bit(c.w, m0, m1, m2, m3);
    } else {
        for (int j = base; j < n && j < base + 4; ++j)
            set_label_bit(C[j], m0, m1, m2, m3);
    }

    #pragma unroll
    for (int off = 32; off > 0; off >>= 1) {
        m0 |= __shfl_down(m0, off, 64);
        m1 |= __shfl_down(m1, off, 64);
        m2 |= __shfl_down(m2, off, 64);
        m3 |= __shfl_down(m3, off, 64);
    }
    if ((threadIdx.x & 63) == 0) {
        if (m0) atomicOr(&sm[0], m0);
        if (m1) atomicOr(&sm[1], m1);
        if (m2) atomicOr(&sm[2], m2);
        if (m3) atomicOr(&sm[3], m3);
    }
    __syncthreads();
    if (threadIdx.x < 4) {
        unsigned v = sm[threadIdx.x];
        if (v) atomicOr(&mask[threadIdx.x], v);
    }
}

// ---------------------------------------------------------------------------
// Pass 2: one thread per float4 (4 consecutive k of one row).
// u and Phi(u) recomputed here (bit-identical); the 32x redundancy per row
// is pure VALU hidden under HBM traffic (verified R3: removing the uphi
// table pass was neutral-to-positive).
__global__ void __launch_bounds__(256) map_kernel(
    const int* __restrict__ C,
    const float* __restrict__ eps,
    const float* __restrict__ mu_p,
    const float* __restrict__ sigma_p,
    const float4* __restrict__ U4,
    const uint4* __restrict__ mask4,
    float4* __restrict__ out4,
    int total4)
{
    int idx = blockIdx.x * blockDim.x + threadIdx.x;
    if (idx >= total4) return;
    int row = idx >> 5;        // K/4 = 32 float4 per row
    int k0  = (idx & 31) << 2;

    float4 Uv = U4[idx];       // plain coalesced load (NT load cost ~9us, R5)
    float  e  = eps[row];      // 32 threads share each value -> L1 broadcast
    int    c  = C[row];
    uint4  w  = *mask4;        // same 16B for all threads -> broadcast

    const float sg = sigma_p[0];   // uniform address -> scalar load
    const float mu = mu_p[0];
    float u   = fmaf(sg, e, mu);
    float phi = 0.5f * erfcf(-u * 0.7071067811865476f);

    // rank = popcount of presence bits strictly below c
    int cw = c >> 5;
    unsigned below = (1u << (c & 31)) - 1u;
    int rank = __popc(w.x & ((0 < cw) ? 0xFFFFFFFFu : ((0 == cw) ? below : 0u)))
             + __popc(w.y & ((1 < cw) ? 0xFFFFFFFFu : ((1 == cw) ? below : 0u)))
             + __popc(w.z & ((2 < cw) ? 0xFFFFFFFFu : ((2 == cw) ? below : 0u)))
             + __popc(w.w & ((3 < cw) ? 0xFFFFFFFFu : ((3 == cw) ? below : 0u)));

    const float lo = 1e-7f;
    const float hi = 0.99999988079071045f;  // fp32(1 - 1e-7), matches jnp.clip

    // clamp via v_med3_f32 (single instruction)
    float p0 = __builtin_amdgcn_fmed3f(Uv.x, lo, hi) * phi;
    float p1 = __builtin_amdgcn_fmed3f(Uv.y, lo, hi) * phi;
    float p2 = __builtin_amdgcn_fmed3f(Uv.z, lo, hi) * phi;
    float p3 = __builtin_amdgcn_fmed3f(Uv.w, lo, hi) * phi;

    float z0 = ndtri_fast(p0);
    float z1 = ndtri_fast(p1);
    float z2 = ndtri_fast(p2);
    float z3 = ndtri_fast(p3);

    vfloat4 o;
    o.x = (k0 + 0 == rank) ? u : z0;
    o.y = (k0 + 1 == rank) ? u : z1;
    o.z = (k0 + 2 == rank) ? u : z2;
    o.w = (k0 + 3 == rank) ? u : z3;

    // out is never re-read: stream it past the caches (full-line coalesced)
    __builtin_nontemporal_store(o, reinterpret_cast<vfloat4*>(&out4[idx]));
}

extern "C" void kernel_launch(void* const* d_in, const int* in_sizes, int n_in,
                              void* d_out, int out_size, void* d_ws, size_t ws_size,
                              hipStream_t stream) {
    const int*   C     = (const int*)d_in[0];
    const float* eps   = (const float*)d_in[1];
    const float4* U4   = (const float4*)d_in[2];
    const float* mu    = (const float*)d_in[3];
    const float* sigma = (const float*)d_in[4];
    float4* out4 = (float4*)d_out;

    unsigned* mask = (unsigned*)d_ws;

    int n = in_sizes[0];           // B*N = 262144 rows
    int total4 = out_size / 4;     // float4 count (unchanged from verified baseline)

    // ws is re-poisoned to 0xAA before every timed launch — zero the bitmap.
    (void)hipMemsetAsync(d_ws, 0, 4 * sizeof(unsigned), stream);

    int n4 = (n + 3) >> 2;
    int bb = (n4 + 255) / 256;
    bitmap_kernel<<<bb, 256, 0, stream>>>(C, mask, n);

    int mb = (total4 + 255) / 256;
    map_kernel<<<mb, 256, 0, stream>>>(C, eps, mu, sigma, U4,
                                       (const uint4*)mask, out4, total4);
}